// Round 1
// baseline (239.759 us; speedup 1.0000x reference)
//
#include <hip/hip_runtime.h>

// Depthwise causal conv1d, channel-last.
// x: (B, L, D) fp32; w: (K, 1, D) fp32; b: (D,) fp32; y: (B, L, D) fp32.
// y[n,l,d] = sum_{k=0}^{K-1} w[k,d] * x[n, l+k-(K-1), d] + b[d]   (zero-pad left)
//
// Memory-bound: 128 MiB in + 128 MiB out => ~42 us floor at 6.3 TB/s.
// Strategy: one thread per (batch, float4 channel group), T consecutive l
// positions per thread with a K-1 register sliding window -> each x element
// read exactly once, each y written once, fully coalesced float4 access.

#define CONV_B 4
#define CONV_L 4096
#define CONV_D 2048
#define CONV_K 4
#define CONV_T 16              // l positions per thread
#define CONV_D4 (CONV_D / 4)   // 512 float4 groups per row

__global__ __launch_bounds__(256) void short_conv_kernel(
    const float* __restrict__ x,
    const float* __restrict__ w,
    const float* __restrict__ bias,
    float* __restrict__ y)
{
    const int gid = blockIdx.x * blockDim.x + threadIdx.x;
    const int d4 = gid % CONV_D4;                  // float4 channel group
    const int rest = gid / CONV_D4;
    const int lchunk = rest % (CONV_L / CONV_T);
    const int b = rest / (CONV_L / CONV_T);
    const int l0 = lchunk * CONV_T;
    const int d = d4 * 4;

    // Row-strided float4 pointers for this (batch, channel-group) column.
    const float4* __restrict__ x4 =
        (const float4*)(x + (size_t)b * CONV_L * CONV_D) + d4;
    float4* __restrict__ y4 =
        (float4*)(y + (size_t)b * CONV_L * CONV_D) + d4;

    // Per-channel weights (K=4 taps) and bias: tiny, L2-resident.
    const float4 w0 = *(const float4*)(w + 0 * CONV_D + d);
    const float4 w1 = *(const float4*)(w + 1 * CONV_D + d);
    const float4 w2 = *(const float4*)(w + 2 * CONV_D + d);
    const float4 w3 = *(const float4*)(w + 3 * CONV_D + d);
    const float4 bv = *(const float4*)(bias + d);

    const float4 zero = make_float4(0.f, 0.f, 0.f, 0.f);

    // Prime the K-1 sliding window (zero-padded at the causal boundary).
    // For l0 > 0 these are re-reads of the previous chunk's tail -> L2 hits.
    float4 xm3 = (l0 >= 3) ? x4[(size_t)(l0 - 3) * CONV_D4] : zero;
    float4 xm2 = (l0 >= 2) ? x4[(size_t)(l0 - 2) * CONV_D4] : zero;
    float4 xm1 = (l0 >= 1) ? x4[(size_t)(l0 - 1) * CONV_D4] : zero;

#pragma unroll
    for (int t = 0; t < CONV_T; ++t) {
        const int l = l0 + t;
        const float4 xc = x4[(size_t)l * CONV_D4];

        float4 r;
        r.x = fmaf(w0.x, xm3.x, fmaf(w1.x, xm2.x, fmaf(w2.x, xm1.x, fmaf(w3.x, xc.x, bv.x))));
        r.y = fmaf(w0.y, xm3.y, fmaf(w1.y, xm2.y, fmaf(w2.y, xm1.y, fmaf(w3.y, xc.y, bv.y))));
        r.z = fmaf(w0.z, xm3.z, fmaf(w1.z, xm2.z, fmaf(w2.z, xm1.z, fmaf(w3.z, xc.z, bv.z))));
        r.w = fmaf(w0.w, xm3.w, fmaf(w1.w, xm2.w, fmaf(w2.w, xm1.w, fmaf(w3.w, xc.w, bv.w))));

        y4[(size_t)l * CONV_D4] = r;

        xm3 = xm2;
        xm2 = xm1;
        xm1 = xc;
    }
}

extern "C" void kernel_launch(void* const* d_in, const int* in_sizes, int n_in,
                              void* d_out, int out_size, void* d_ws, size_t ws_size,
                              hipStream_t stream) {
    const float* x = (const float*)d_in[0];
    const float* w = (const float*)d_in[1];
    const float* b = (const float*)d_in[2];
    float* y = (float*)d_out;

    const int total_threads = CONV_B * (CONV_L / CONV_T) * CONV_D4; // 524288
    const int block = 256;
    const int grid = total_threads / block;                          // 2048

    short_conv_kernel<<<grid, block, 0, stream>>>(x, w, b, y);
}

// Round 3
// 231.516 us; speedup vs baseline: 1.0356x; 1.0356x over previous
//
#include <hip/hip_runtime.h>

// Depthwise causal conv1d, channel-last. x:(B,L,D) f32, w:(K,1,D), b:(D), y:(B,L,D).
// y[n,l,d] = sum_k w[k,d]*x[n,l+k-3,d] + b[d], zero-padded left.
//
// Memory-bound: ~256 MiB total HBM traffic -> ~40 us floor at 6.3 TB/s.
// R1 lesson: sliding-window loop compiled to 24 VGPRs = ONE outstanding load
// per wave -> 2.56 TB/s (MLP-starved, not HBM-bound). Fix: batch-issue all
// T+3 independent loads into a register array before any use, so the wave
// keeps ~11 KiB in flight. T=8 keeps VGPRs ~70 (=> ~7 waves/SIMD).
// R2 lesson: __builtin_nontemporal_store needs a native vector type, not
// HIP_vector_type -> use ext_vector_type(4) float for the store.

#define CONV_B 4
#define CONV_L 4096
#define CONV_D 2048
#define CONV_K 4
#define CONV_T 8               // l positions per thread
#define CONV_D4 (CONV_D / 4)   // 512 float4 groups per row
#define CONV_LC (CONV_L / CONV_T)

typedef float nfloat4 __attribute__((ext_vector_type(4)));  // native vec for nt-store

__global__ __launch_bounds__(256) void short_conv_kernel(
    const float* __restrict__ x,
    const float* __restrict__ w,
    const float* __restrict__ bias,
    float* __restrict__ y)
{
    const int gid = blockIdx.x * blockDim.x + threadIdx.x;
    const int d4 = gid % CONV_D4;                  // float4 channel group
    const int rest = gid / CONV_D4;
    const int lchunk = rest % CONV_LC;
    const int b = rest / CONV_LC;
    const int l0 = lchunk * CONV_T;
    const int d = d4 * 4;

    const float4* __restrict__ x4 =
        (const float4*)(x + (size_t)b * CONV_L * CONV_D) + d4;
    float4* __restrict__ y4 =
        (float4*)(y + (size_t)b * CONV_L * CONV_D) + d4;

    const float4 zero = make_float4(0.f, 0.f, 0.f, 0.f);

    // ---- Phase 1: issue ALL independent global loads up front ----
    // 8 body rows + 3 priming rows: 11 outstanding 1-KiB wave-loads.
    float4 xc[CONV_T];
#pragma unroll
    for (int t = 0; t < CONV_T; ++t) {
        xc[t] = x4[(size_t)(l0 + t) * CONV_D4];
    }
    // Priming window (re-reads of previous chunk's tail -> L2/L3 hits;
    // zero at the causal boundary).
    float4 xm3 = (l0 >= 3) ? x4[(size_t)(l0 - 3) * CONV_D4] : zero;
    float4 xm2 = (l0 >= 2) ? x4[(size_t)(l0 - 2) * CONV_D4] : zero;
    float4 xm1 = (l0 >= 1) ? x4[(size_t)(l0 - 1) * CONV_D4] : zero;

    // Weights + bias (tiny, L2-resident after first touch).
    const float4 w0 = *(const float4*)(w + 0 * CONV_D + d);
    const float4 w1 = *(const float4*)(w + 1 * CONV_D + d);
    const float4 w2 = *(const float4*)(w + 2 * CONV_D + d);
    const float4 w3 = *(const float4*)(w + 3 * CONV_D + d);
    const float4 bv = *(const float4*)(bias + d);

    // ---- Phase 2: compute + nontemporal store (y is write-only stream;
    // don't evict L3-resident x). ----
#pragma unroll
    for (int t = 0; t < CONV_T; ++t) {
        const float4 a3 = xm3, a2 = xm2, a1 = xm1, a0 = xc[t];
        nfloat4 r;
        r.x = fmaf(w0.x, a3.x, fmaf(w1.x, a2.x, fmaf(w2.x, a1.x, fmaf(w3.x, a0.x, bv.x))));
        r.y = fmaf(w0.y, a3.y, fmaf(w1.y, a2.y, fmaf(w2.y, a1.y, fmaf(w3.y, a0.y, bv.y))));
        r.z = fmaf(w0.z, a3.z, fmaf(w1.z, a2.z, fmaf(w2.z, a1.z, fmaf(w3.z, a0.z, bv.z))));
        r.w = fmaf(w0.w, a3.w, fmaf(w1.w, a2.w, fmaf(w2.w, a1.w, fmaf(w3.w, a0.w, bv.w))));

        __builtin_nontemporal_store(r, (nfloat4*)&y4[(size_t)(l0 + t) * CONV_D4]);

        xm3 = xm2;
        xm2 = xm1;
        xm1 = a0;
    }
}

extern "C" void kernel_launch(void* const* d_in, const int* in_sizes, int n_in,
                              void* d_out, int out_size, void* d_ws, size_t ws_size,
                              hipStream_t stream) {
    const float* x = (const float*)d_in[0];
    const float* w = (const float*)d_in[1];
    const float* b = (const float*)d_in[2];
    float* y = (float*)d_out;

    const int total_threads = CONV_B * CONV_LC * CONV_D4;  // 1,048,576
    const int block = 256;
    const int grid = total_threads / block;                // 4096

    short_conv_kernel<<<grid, block, 0, stream>>>(x, w, b, y);
}

// Round 4
// 230.456 us; speedup vs baseline: 1.0404x; 1.0046x over previous
//
#include <hip/hip_runtime.h>
#include <stdint.h>

// Depthwise causal conv1d, channel-last. x:(B,L,D) f32, w:(K,1,D), b:(D), y:(B,L,D).
// y[n,l,d] = sum_k w[k,d]*x[n,l+k-3,d] + b[d], zero-padded left.
//
// R3 lesson: VGPR-destination loads get serialized by the register allocator
// (VGPR=44 => ~1 outstanding load/wave => 2.87 TB/s). Fix: stage x through LDS
// with __builtin_amdgcn_global_load_lds (width 16) -- fire-and-forget, zero
// destination VGPRs, cannot be sunk by the scheduler. 35 KB in flight per
// block x 4 blocks/CU >> Little's-law requirement (~20 KB/CU).

#define CB 4
#define CL 4096
#define CD 2048
#define STRIP 256               // floats per channel strip (1 KB per row-strip)
#define SF4 (STRIP / 4)         // 64 float4 per row-strip = one wave-load
#define ROWS 32                 // output rows per block
#define HALO 3
#define LROWS (ROWS + HALO)     // 35 staged rows
#define NSTRIP (CD / STRIP)     // 8
#define NCHUNK (CL / ROWS)      // 128

typedef float nfloat4 __attribute__((ext_vector_type(4)));

__global__ __launch_bounds__(256) void short_conv_kernel(
    const float* __restrict__ x,
    const float* __restrict__ w,
    const float* __restrict__ bias,
    float* __restrict__ y)
{
    __shared__ float lds[LROWS * STRIP];   // 35 KB -> 4 blocks/CU

    const int tid  = threadIdx.x;
    const int lane = tid & 63;
    const int wv   = tid >> 6;

    const int bid    = blockIdx.x;
    const int strip  = bid & (NSTRIP - 1);
    const int lchunk = (bid >> 3) & (NCHUNK - 1);
    const int b      = bid >> 10;

    const int l0 = lchunk * ROWS;
    const int c0 = strip * STRIP;

    const float* xs = x + (size_t)b * CL * CD + c0;   // strip base, row stride CD
    float*       ys = y + (size_t)b * CL * CD + c0;

    // Zero the 3 causal-halo rows for the first chunk (768 float4 = 192 threads).
    // Wave-uniform branch (waves 0-2 all true, wave 3 all false).
    if (l0 == 0 && tid < HALO * SF4) {
        ((float4*)lds)[tid] = make_float4(0.f, 0.f, 0.f, 0.f);
    }

    // ---- Stage LROWS row-strips: LDS row r <- global row (l0 - 3 + r). ----
    // One wave-instruction moves one full 1 KB row-strip (lane i -> base+16i).
    // Fire-and-forget: ~9 KB outstanding per wave, no destination VGPRs.
    for (int r = wv; r < LROWS; r += 4) {
        const int l = l0 - HALO + r;               // wave-uniform
        if (l >= 0) {
            const float* gsrc = xs + (size_t)l * CD + lane * 4;
            float* ldst = &lds[r * STRIP + lane * 4];
            __builtin_amdgcn_global_load_lds(
                (const __attribute__((address_space(1))) uint32_t*)gsrc,
                (__attribute__((address_space(3))) uint32_t*)ldst,
                16, 0, 0);
        }
    }

    // Per-lane weights/bias for columns c0 + lane*4 .. +3 (L2-resident, tiny).
    const float4 w0 = *(const float4*)(w + 0 * CD + c0 + lane * 4);
    const float4 w1 = *(const float4*)(w + 1 * CD + c0 + lane * 4);
    const float4 w2 = *(const float4*)(w + 2 * CD + c0 + lane * 4);
    const float4 w3 = *(const float4*)(w + 3 * CD + c0 + lane * 4);
    const float4 bv = *(const float4*)(bias + c0 + lane * 4);

    __syncthreads();   // drains vmcnt (load_lds) + lgkmcnt (halo zeros)

    // ---- Compute: wave wv owns output rows wv*8 .. wv*8+7. ----
    // Register sliding window: 11 ds_read_b128 per wave for 8 outputs.
    const int o0 = wv * 8;
    const float4* lrow = (const float4*)lds + lane;     // row stride SF4

    float4 xm3 = lrow[(o0 + 0) * SF4];
    float4 xm2 = lrow[(o0 + 1) * SF4];
    float4 xm1 = lrow[(o0 + 2) * SF4];

#pragma unroll
    for (int t = 0; t < 8; ++t) {
        const float4 a0 = lrow[(o0 + t + HALO) * SF4];

        nfloat4 r;
        r.x = fmaf(w0.x, xm3.x, fmaf(w1.x, xm2.x, fmaf(w2.x, xm1.x, fmaf(w3.x, a0.x, bv.x))));
        r.y = fmaf(w0.y, xm3.y, fmaf(w1.y, xm2.y, fmaf(w2.y, xm1.y, fmaf(w3.y, a0.y, bv.y))));
        r.z = fmaf(w0.z, xm3.z, fmaf(w1.z, xm2.z, fmaf(w2.z, xm1.z, fmaf(w3.z, a0.z, bv.z))));
        r.w = fmaf(w0.w, xm3.w, fmaf(w1.w, xm2.w, fmaf(w2.w, xm1.w, fmaf(w3.w, a0.w, bv.w))));

        const int l = l0 + o0 + t;
        __builtin_nontemporal_store(r, (nfloat4*)(ys + (size_t)l * CD + lane * 4));

        xm3 = xm2;
        xm2 = xm1;
        xm1 = a0;
    }
}

extern "C" void kernel_launch(void* const* d_in, const int* in_sizes, int n_in,
                              void* d_out, int out_size, void* d_ws, size_t ws_size,
                              hipStream_t stream) {
    const float* x = (const float*)d_in[0];
    const float* w = (const float*)d_in[1];
    const float* b = (const float*)d_in[2];
    float* y = (float*)d_out;

    const int grid = CB * NCHUNK * NSTRIP;   // 4 * 128 * 8 = 4096 blocks
    short_conv_kernel<<<grid, 256, 0, stream>>>(x, w, b, y);
}